// Round 7
// baseline (161.408 us; speedup 1.0000x reference)
//
#include <hip/hip_runtime.h>

#define RAD 8
#define HH 256
#define WW 256
#define NC 12
#define PS (HH*WW)
#define SCALE (255.0f/1023.0f)

// ---- tile geometry (64x64 HR tile) ----
#define NA2 36      // A/B halo tile rows/cols (20 center + 8 halo each side)
#define NC2 20      // center rows/cols (18 exact + 2 slack)
#define AP2 37      // LDS stride for A/B tile (37%32=5, conflict-free)
#define HP2 21      // LDS stride for H-boxed / final tiles

__device__ __forceinline__ int swz3072(int b) { return (b & 7) * 384 + (b >> 3); }

// run17: lane l returns sum of x over lanes [l-16, l] (valid for l >= 16).
__device__ __forceinline__ float run17(float x) {
    float s = x + __shfl_up(x, 1, 64);
    s += __shfl_up(s, 2, 64);
    s += __shfl_up(s, 4, 64);
    s += __shfl_up(s, 8, 64);      // sum of lanes [l-15, l]
    s += __shfl_up(x, 16, 64);     // + lane l-16 -> 17-wide
    return s;
}

// ---------- K0: global sum of |l_a|+eps ----------
__global__ __launch_bounds__(256) void k_reduce(const float* __restrict__ la,
                                                float* __restrict__ partials) {
    int tid = threadIdx.x;
    __shared__ float ls[4];
    const float4* p4 = (const float4*)la;
    int base = blockIdx.x * 2048 + tid;
    float s = 0.f;
    #pragma unroll
    for (int i = 0; i < 8; i++) {
        float4 v = p4[base + i * 256];
        s += (fabsf(v.x) + 1e-12f) + (fabsf(v.y) + 1e-12f) +
             (fabsf(v.z) + 1e-12f) + (fabsf(v.w) + 1e-12f);
    }
    for (int off = 32; off > 0; off >>= 1) s += __shfl_down(s, off, 64);
    int lane = tid & 63, wid = tid >> 6;
    if (lane == 0) ls[wid] = s;
    __syncthreads();
    if (tid == 0) partials[blockIdx.x] = ls[0] + ls[1] + ls[2] + ls[3];
}

// ---------- K1: fully fused per-64x64-HR-tile kernel ----------
// Phase A: 4 waves compute the 36x36 A/b halo tile from raw inputs
//          (register running sums + run17, no LDS for raw data).
// Phases 2-4: verbatim round-6 passing code (H-box, V-box/N, resize+fuse).
// 3072 blocks, 256 threads, 16.3 KB LDS -> 8 blocks/CU.
__global__ __launch_bounds__(256) void k_tile(const float* __restrict__ la,
                                              const float* __restrict__ lx,
                                              const float* __restrict__ ly,
                                              const float* __restrict__ hrx,
                                              const float* __restrict__ partials,
                                              float* __restrict__ out) {
    __shared__ float sA[NA2 * AP2], sB[NA2 * AP2];   // 36x36 A/B halo tiles
    __shared__ float sHA[NA2 * HP2], sHB[NA2 * HP2]; // H-boxed [36][20]
    float* mAb = sA;                                 // alias: sA/sB dead after phase 2
    float* mBb = sB;

    int tid = threadIdx.x, lane = tid & 63, wv = tid >> 6;
    int b  = swz3072(blockIdx.x);
    int p  = b >> 8;                 // plane 0..11
    int t  = b & 255;
    int ti = t >> 4, tj = t & 15;    // 16x16 tiles of 64x64
    int I0 = ti << 6, J0 = tj << 6;
    int Lr0 = max(0, (I0 * 255) / 1023 - 1);
    int Lc0 = max(0, (J0 * 255) / 1023 - 1);

    // invS from the 96 per-block partials (per-wave reduce, no barrier)
    float psum = partials[lane] + ((lane < 32) ? partials[lane + 64] : 0.0f);
    #pragma unroll
    for (int off = 32; off > 0; off >>= 1) psum += __shfl_xor(psum, off, 64);
    float invS = 1.0f / psum;

    // ---- phase A: wave wv computes A/b rows [Lr0-8+9*wv .. +8] into sA/sB ----
    {
        int C0  = Lc0 - 8;                   // first A-col of the tile
        int col = C0 - 8 + lane;             // raw product column for this lane
        bool vc = (col >= 0) && (col < WW);
        int colc = min(max(col, 0), WW - 1);
        const float* pa = la + p * PS + colc;
        const float* px = lx + p * PS + colc;
        const float* py = ly + p * PS + colc;

        int  cA    = C0 - 16 + lane;         // A-col center (lane 16 -> C0)
        int  cIdx  = lane - 16;              // LDS col index
        bool vLane = (lane >= 16) && (lane < 16 + NA2);
        bool vcA   = (cA >= 0) && (cA < WW);
        float cxA  = (float)(min(cA + RAD, WW - 1) - max(cA - RAD, 0) + 1);

        float s0 = 0, s1 = 0, s2 = 0, s3 = 0, s4 = 0, s5 = 0;
        auto accum = [&](int rr, float sg) {
            float va = 0.f, vx = 0.f, vy = 0.f;
            if (vc) { int o = rr * WW; va = pa[o]; vx = px[o]; vy = py[o]; }
            float a  = vc ? (fabsf(va) + 1e-12f) : 0.f;   // exact 0 outside image
            float ax = a * vx, ay = a * vy;
            s0 = fmaf(sg, a, s0); s1 = fmaf(sg, ax, s1); s2 = fmaf(sg, ay, s2);
            s3 = fmaf(sg, a * ax, s3); s4 = fmaf(sg, ax * ax, s4); s5 = fmaf(sg, ax * ay, s5);
        };

        int R0 = Lr0 - 8 + 9 * wv;           // first A-row for this wave
        // warm-up vertical window rows [R0-8, R0+8]
        #pragma unroll
        for (int d = -8; d <= 8; ++d) {
            int rr = R0 + d;
            if (rr >= 0 && rr < HH) accum(rr, 1.0f);
        }
        #pragma unroll
        for (int k = 0; k < 9; ++k) {
            int m = R0 + k;                  // A-row (may lie outside [0,255])
            if (k > 0) {
                int ra = m + 8; if (ra >= 0 && ra < HH) accum(ra, 1.0f);
                int rs = m - 9; if (rs >= 0 && rs < HH) accum(rs, -1.0f);
            }
            float h0 = run17(s0), h1 = run17(s1), h2 = run17(s2),
                  h3 = run17(s3), h4 = run17(s4), h5 = run17(s5);
            float Av = 0.f, bv = 0.f;
            if (m >= 0 && m < HH) {          // wave-uniform branch
                float cy = (float)(min(m + RAD, HH - 1) - max(m - RAD, 0) + 1);
                float Nv = cxA * cy, invN = 1.0f / Nv;
                float m_a = h0 * invN, m_ax = h1 * invN, m_ay = h2 * invN;
                float m_tax = h3 * invN * invS;
                float m_a2x2 = h4 * invN, m_a2xy = h5 * invN;
                float tempv = fabsf(m_a2x2 - Nv * m_tax * m_ax);
                float Avt = (m_a2xy - Nv * m_tax * m_ay) / (tempv + 1e-8f);
                float bvt = (m_ay - Avt * m_ax) / m_a;
                if (vcA) { Av = Avt; bv = bvt; }   // out-of-image cols stay exactly 0
            }
            if (vLane) {
                int rIdx = 9 * wv + k;       // tile row 0..35
                sA[rIdx * AP2 + cIdx] = Av;
                sB[rIdx * AP2 + cIdx] = bv;
            }
        }
    }
    __syncthreads();

    // ---- phase 2: horizontal 17-tap (direct, fully parallel) -> sHA/sHB [36][20]
    for (int job = tid; job < 2 * NA2 * NC2; job += 256) {
        int which = (job >= NA2 * NC2);
        int rest  = which ? job - NA2 * NC2 : job;
        int r = rest / NC2, c = rest - r * NC2;
        const float* rp = (which ? sB : sA) + r * AP2 + c;
        float s = 0.f;
        #pragma unroll
        for (int j = 0; j < 17; ++j) s += rp[j];
        (which ? sHB : sHA)[r * HP2 + c] = s;
    }
    __syncthreads();

    // ---- phase 3: vertical 17-tap + /N -> mAb/mBb [20][21] (alias over sA/sB)
    for (int job = tid; job < 2 * NC2 * NC2; job += 256) {
        int which = (job >= NC2 * NC2);
        int rest  = which ? job - NC2 * NC2 : job;
        int r = rest / NC2, c = rest - r * NC2;
        const float* sp = (which ? sHB : sHA) + r * HP2 + c;
        float s = 0.f;
        #pragma unroll
        for (int j = 0; j < 17; ++j) s += sp[j * HP2];
        int gj = Lc0 + c, gi = Lr0 + r;
        float cxw = (float)(min(gj + RAD, WW - 1) - max(gj - RAD, 0) + 1);
        float cyw = (float)(min(gi + RAD, HH - 1) - max(gi - RAD, 0) + 1);
        (which ? mBb : mAb)[r * HP2 + c] = s / (cxw * cyw);
    }
    __syncthreads();

    // ---- phase 4: bilinear upsample from LDS + fuse with hr_x (verbatim passing math;
    // all 4 hr_x float4 loads issued up front for 4-deep per-lane MLP)
    {
        int col4 = tid & 15;                 // float4 column in 64-wide tile
        int rg   = tid >> 4;                 // 0..15 row group
        int J4 = (J0 >> 2) + col4;
        int Jp = J4 << 2;
        int xb = (int)((float)Jp * SCALE);
        int i1 = min(xb + 1, WW - 1), i2 = min(xb + 2, WW - 1);
        int lxb = xb - Lc0, li1 = i1 - Lc0, li2 = i2 - Lc0;   // in [0,19]
        float wxv[4]; bool hs[4];
        #pragma unroll
        for (int k = 0; k < 4; k++) {
            float xsk = (float)(Jp + k) * SCALE;
            int x0 = (int)xsk;
            wxv[k] = xsk - (float)x0;
            hs[k] = (x0 > xb);
        }
        const float4* h4 = (const float4*)hrx;
        float4* o4 = (float4*)out;
        int planeHR = p * 262144;            // 1024*256 float4 per plane

        int hidx0 = planeHR + (I0 + 0 * 16 + rg) * 256 + J4;
        int hidx1 = planeHR + (I0 + 1 * 16 + rg) * 256 + J4;
        int hidx2 = planeHR + (I0 + 2 * 16 + rg) * 256 + J4;
        int hidx3 = planeHR + (I0 + 3 * 16 + rg) * 256 + J4;
        float4 hp0 = h4[hidx0], hp1 = h4[hidx1], hp2 = h4[hidx2], hp3 = h4[hidx3];

        #pragma unroll
        for (int it = 0; it < 4; ++it) {
            int row = (it << 4) + rg;        // 0..63
            int I = I0 + row;
            float ysf = (float)I * SCALE;
            int y0 = (int)ysf;
            float wy = ysf - (float)y0;
            int y1 = min(y0 + 1, HH - 1);
            int ly0 = y0 - Lr0, ly1 = y1 - Lr0;   // in [0,19]
            const float* a0p = mAb + ly0 * HP2;
            const float* a1p = mAb + ly1 * HP2;
            const float* b0p = mBb + ly0 * HP2;
            const float* b1p = mBb + ly1 * HP2;
            float A0a = a0p[lxb], A0b = a0p[li1], A0c = a0p[li2];
            float A1a = a1p[lxb], A1b = a1p[li1], A1c = a1p[li2];
            float B0a = b0p[lxb], B0b = b0p[li1], B0c = b0p[li2];
            float B1a = b1p[lxb], B1b = b1p[li1], B1c = b1p[li2];
            float4 h = (it == 0) ? hp0 : (it == 1) ? hp1 : (it == 2) ? hp2 : hp3;
            int hidx = (it == 0) ? hidx0 : (it == 1) ? hidx1 : (it == 2) ? hidx2 : hidx3;
            float hv[4] = {h.x, h.y, h.z, h.w};
            float ov[4];
            float omwy = 1.0f - wy;
            #pragma unroll
            for (int k = 0; k < 4; k++) {
                bool hb = hs[k];
                float Alo0 = hb ? A0b : A0a, Ahi0 = hb ? A0c : A0b;
                float Alo1 = hb ? A1b : A1a, Ahi1 = hb ? A1c : A1b;
                float Blo0 = hb ? B0b : B0a, Bhi0 = hb ? B0c : B0b;
                float Blo1 = hb ? B1b : B1a, Bhi1 = hb ? B1c : B1b;
                float wx = wxv[k], omwx = 1.0f - wx;
                float Ar0 = Alo0 * omwx + Ahi0 * wx;
                float Ar1 = Alo1 * omwx + Ahi1 * wx;
                float Br0 = Blo0 * omwx + Bhi0 * wx;
                float Br1 = Blo1 * omwx + Bhi1 * wx;
                float Avv = Ar0 * omwy + Ar1 * wy;
                float Bvv = Br0 * omwy + Br1 * wy;
                ov[k] = Avv * hv[k] + Bvv;
            }
            float4 o; o.x = ov[0]; o.y = ov[1]; o.z = ov[2]; o.w = ov[3];
            o4[hidx] = o;
        }
    }
}

extern "C" void kernel_launch(void* const* d_in, const int* in_sizes, int n_in,
                              void* d_out, int out_size, void* d_ws, size_t ws_size,
                              hipStream_t stream) {
    const float* lr_x = (const float*)d_in[0];
    const float* lr_y = (const float*)d_in[1];
    const float* hr_x = (const float*)d_in[2];
    const float* l_a  = (const float*)d_in[3];
    float* out = (float*)d_out;
    float* partials = (float*)d_ws;   // 96 floats

    k_reduce<<<96, 256, 0, stream>>>(l_a, partials);
    k_tile  <<<3072, 256, 0, stream>>>(l_a, lr_x, lr_y, hr_x, partials, out);
}

// Round 8
// 135.908 us; speedup vs baseline: 1.1876x; 1.1876x over previous
//
#include <hip/hip_runtime.h>

#define RAD 8
#define HH 256
#define WW 256
#define NC 12
#define PS (HH*WW)
#define SCALE (255.0f/1023.0f)

// ---- k_tile geometry (64x64 HR tile) ----
#define NR3 36      // HA/HB halo rows (20 center + 8 halo each side)
#define NC3 20      // center rows/cols (18 exact + 2 slack)
#define P3  21      // LDS stride

__device__ __forceinline__ int swz3072(int b) { return (b & 7) * 384 + (b >> 3); }
__device__ __forceinline__ int swz1536(int b) { return (b & 7) * 192 + (b >> 3); }

// run17: lane l returns sum of x over lanes [l-16, l] (valid for l >= 16).
__device__ __forceinline__ float run17(float x) {
    float s = x + __shfl_up(x, 1, 64);
    s += __shfl_up(s, 2, 64);
    s += __shfl_up(s, 4, 64);
    s += __shfl_up(s, 8, 64);      // sum of lanes [l-15, l]
    s += __shfl_up(x, 16, 64);     // + lane l-16 -> 17-wide
    return s;
}

// ---------- K0: global sum of |l_a|+eps ----------
__global__ __launch_bounds__(256) void k_reduce(const float* __restrict__ la,
                                                float* __restrict__ partials) {
    int tid = threadIdx.x;
    __shared__ float ls[4];
    const float4* p4 = (const float4*)la;
    int base = blockIdx.x * 2048 + tid;
    float s = 0.f;
    #pragma unroll
    for (int i = 0; i < 8; i++) {
        float4 v = p4[base + i * 256];
        s += (fabsf(v.x) + 1e-12f) + (fabsf(v.y) + 1e-12f) +
             (fabsf(v.z) + 1e-12f) + (fabsf(v.w) + 1e-12f);
    }
    for (int off = 32; off > 0; off >>= 1) s += __shfl_down(s, off, 64);
    int lane = tid & 63, wid = tid >> 6;
    if (lane == 0) ls[wid] = s;
    __syncthreads();
    if (tid == 0) partials[blockIdx.x] = ls[0] + ls[1] + ls[2] + ls[3];
}

// ---------- K1: A,b once per LR pixel + horizontal box of A,b (double run17 cascade) ----------
// Wave = 32-col x 4-row patch of HA/HB. Product col = C0 - 16 + lane.
// Stage 1 run17 -> A/b at cA = C0 - 24 + lane (valid lanes >= 16, gated to 0 off-image).
// Stage 2 run17 -> HA/HB at cM = C0 - 32 + lane (lanes 32..63 -> cols C0..C0+31).
// Windows of stage-2 output lanes (>=32) only touch lanes >= 16 (garbage never propagates).
__global__ __launch_bounds__(256) void k_ab(const float* __restrict__ la,
                                            const float* __restrict__ lx,
                                            const float* __restrict__ ly,
                                            const float* __restrict__ partials,
                                            float* __restrict__ HA,
                                            float* __restrict__ HB) {
    int tid = threadIdx.x, lane = tid & 63, wv = tid >> 6;
    int gw = swz1536(blockIdx.x) * 4 + wv;       // 0..6143
    int p  = gw >> 9;                            // plane 0..11
    int r  = gw & 511;
    int strip = r >> 6;                          // 0..7 (32-col strips)
    int band  = r & 63;                          // 0..63 (4-row bands)
    int i0 = band << 2;
    int C0 = strip << 5;
    int col = C0 - 16 + lane;                    // product column
    bool vc = (col >= 0) && (col < WW);
    int colc = min(max(col, 0), WW - 1);
    const float* pa = la + p * PS + colc;
    const float* px = lx + p * PS + colc;
    const float* py = ly + p * PS + colc;

    // invS from the 96 per-block partials (wave-local, no barrier)
    float psum = partials[lane] + ((lane < 32) ? partials[lane + 64] : 0.0f);
    #pragma unroll
    for (int off = 32; off > 0; off >>= 1) psum += __shfl_xor(psum, off, 64);
    float invS = 1.0f / psum;

    int  cA  = C0 - 24 + lane;                   // stage-1 center col
    bool vcA = (cA >= 0) && (cA < WW);
    float cxA = (float)(min(cA + RAD, WW - 1) - max(cA - RAD, 0) + 1);
    int  cM  = C0 - 32 + lane;                   // stage-2 center col (lanes 32..63)

    float s0 = 0, s1 = 0, s2 = 0, s3 = 0, s4 = 0, s5 = 0;
    auto accum = [&](int rr, float sg) {
        float va = 0.f, vx = 0.f, vy = 0.f;
        if (vc) { int o = rr * WW; va = pa[o]; vx = px[o]; vy = py[o]; }
        float a  = vc ? (fabsf(va) + 1e-12f) : 0.f;   // exact 0 outside image
        float ax = a * vx, ay = a * vy;
        s0 = fmaf(sg, a, s0); s1 = fmaf(sg, ax, s1); s2 = fmaf(sg, ay, s2);
        s3 = fmaf(sg, a * ax, s3); s4 = fmaf(sg, ax * ax, s4); s5 = fmaf(sg, ax * ay, s5);
    };

    // warm-up vertical window rows [i0-8, i0+8]
    #pragma unroll
    for (int d = -8; d <= 8; ++d) {
        int rr = i0 + d;
        if (rr >= 0 && rr < HH) accum(rr, 1.0f);
    }

    float* HApl = HA + p * PS;
    float* HBpl = HB + p * PS;
    #pragma unroll
    for (int k = 0; k < 4; ++k) {
        int m = i0 + k;                          // in [0,255]
        if (k > 0) {
            int ra = m + 8; if (ra < HH) accum(ra, 1.0f);
            int rs = m - 9; if (rs >= 0) accum(rs, -1.0f);
        }
        float h0 = run17(s0), h1 = run17(s1), h2 = run17(s2),
              h3 = run17(s3), h4 = run17(s4), h5 = run17(s5);
        float cy = (float)(min(m + RAD, HH - 1) - max(m - RAD, 0) + 1);
        float Nv = cxA * cy, invN = 1.0f / Nv;
        float m_a = h0 * invN, m_ax = h1 * invN, m_ay = h2 * invN;
        float m_tax = h3 * invN * invS;
        float m_a2x2 = h4 * invN, m_a2xy = h5 * invN;
        float tempv = fabsf(m_a2x2 - Nv * m_tax * m_ax);
        float Avt = (m_a2xy - Nv * m_tax * m_ay) / (tempv + 1e-8f);
        float bvt = (m_ay - Avt * m_ax) / m_a;
        float Av = vcA ? Avt : 0.f;              // off-image cols contribute exact 0
        float bv = vcA ? bvt : 0.f;
        float HtA = run17(Av), HtB = run17(bv);  // stage-2: H-box of A,b
        if (lane >= 32) {
            int o = m * WW + cM;                 // cM in [C0, C0+31] subset of [0,255]
            HApl[o] = HtA;
            HBpl[o] = HtB;
        }
    }
}

// ---------- K2: per-64x64-HR-tile: vertical box of HA/HB + /N + bilinear resize + fuse ----------
// 3072 blocks, 256 threads, 9.4 KB LDS -> 8 blocks/CU.
__global__ __launch_bounds__(256) void k_tile(const float* __restrict__ HA,
                                              const float* __restrict__ HB,
                                              const float* __restrict__ hrx,
                                              float* __restrict__ out) {
    __shared__ float sHA[NR3 * P3], sHB[NR3 * P3];   // [36][20] halo tiles
    __shared__ float mAb[NC3 * P3], mBb[NC3 * P3];   // [20][20] means

    int tid = threadIdx.x;
    int b  = swz3072(blockIdx.x);
    int p  = b >> 8;                 // plane 0..11
    int t  = b & 255;
    int ti = t >> 4, tj = t & 15;    // 16x16 tiles of 64x64
    int I0 = ti << 6, J0 = tj << 6;
    int Lr0 = max(0, (I0 * 255) / 1023 - 1);
    int Lc0 = max(0, (J0 * 255) / 1023 - 1);

    // phase 1: load 36x20 HA/HB region (row halo only), zero-padded outside image
    const float* HApl = HA + p * PS;
    const float* HBpl = HB + p * PS;
    for (int idx = tid; idx < NR3 * NC3; idx += 256) {
        int r = idx / NC3, c = idx - r * NC3;
        int gr = Lr0 - 8 + r, gc = Lc0 + c;
        float av = 0.f, bv = 0.f;
        if (gr >= 0 && gr < HH && gc < WW) {
            int o = gr * WW + gc;
            av = HApl[o]; bv = HBpl[o];
        }
        sHA[r * P3 + c] = av;
        sHB[r * P3 + c] = bv;
    }
    __syncthreads();

    // phase 2: vertical 17-tap + /N -> mAb/mBb [20][20]
    for (int job = tid; job < 2 * NC3 * NC3; job += 256) {
        int which = (job >= NC3 * NC3);
        int rest  = which ? job - NC3 * NC3 : job;
        int r = rest / NC3, c = rest - r * NC3;
        const float* sp = (which ? sHB : sHA) + r * P3 + c;
        float s = 0.f;
        #pragma unroll
        for (int j = 0; j < 17; ++j) s += sp[j * P3];
        int gj = Lc0 + c, gi = Lr0 + r;
        float cxw = (float)(min(gj + RAD, WW - 1) - max(gj - RAD, 0) + 1);
        float cyw = (float)(min(gi + RAD, HH - 1) - max(gi - RAD, 0) + 1);
        (which ? mBb : mAb)[r * P3 + c] = s / (cxw * cyw);
    }
    __syncthreads();

    // phase 3: bilinear upsample from LDS + fuse with hr_x (verbatim passing math;
    // all 4 hr_x float4 loads issued up front for 4-deep per-lane MLP)
    {
        int col4 = tid & 15;                 // float4 column in 64-wide tile
        int rg   = tid >> 4;                 // 0..15 row group
        int J4 = (J0 >> 2) + col4;
        int Jp = J4 << 2;
        int xb = (int)((float)Jp * SCALE);
        int i1 = min(xb + 1, WW - 1), i2 = min(xb + 2, WW - 1);
        int lxb = xb - Lc0, li1 = i1 - Lc0, li2 = i2 - Lc0;   // in [0,19]
        float wxv[4]; bool hs[4];
        #pragma unroll
        for (int k = 0; k < 4; k++) {
            float xsk = (float)(Jp + k) * SCALE;
            int x0 = (int)xsk;
            wxv[k] = xsk - (float)x0;
            hs[k] = (x0 > xb);
        }
        const float4* h4 = (const float4*)hrx;
        float4* o4 = (float4*)out;
        int planeHR = p * 262144;            // 1024*256 float4 per plane

        int hidx0 = planeHR + (I0 + 0 * 16 + rg) * 256 + J4;
        int hidx1 = planeHR + (I0 + 1 * 16 + rg) * 256 + J4;
        int hidx2 = planeHR + (I0 + 2 * 16 + rg) * 256 + J4;
        int hidx3 = planeHR + (I0 + 3 * 16 + rg) * 256 + J4;
        float4 hp0 = h4[hidx0], hp1 = h4[hidx1], hp2 = h4[hidx2], hp3 = h4[hidx3];

        #pragma unroll
        for (int it = 0; it < 4; ++it) {
            int row = (it << 4) + rg;        // 0..63
            int I = I0 + row;
            float ysf = (float)I * SCALE;
            int y0 = (int)ysf;
            float wy = ysf - (float)y0;
            int y1 = min(y0 + 1, HH - 1);
            int ly0 = y0 - Lr0, ly1 = y1 - Lr0;   // in [0,19]
            const float* a0p = mAb + ly0 * P3;
            const float* a1p = mAb + ly1 * P3;
            const float* b0p = mBb + ly0 * P3;
            const float* b1p = mBb + ly1 * P3;
            float A0a = a0p[lxb], A0b = a0p[li1], A0c = a0p[li2];
            float A1a = a1p[lxb], A1b = a1p[li1], A1c = a1p[li2];
            float B0a = b0p[lxb], B0b = b0p[li1], B0c = b0p[li2];
            float B1a = b1p[lxb], B1b = b1p[li1], B1c = b1p[li2];
            float4 h = (it == 0) ? hp0 : (it == 1) ? hp1 : (it == 2) ? hp2 : hp3;
            int hidx = (it == 0) ? hidx0 : (it == 1) ? hidx1 : (it == 2) ? hidx2 : hidx3;
            float hv[4] = {h.x, h.y, h.z, h.w};
            float ov[4];
            float omwy = 1.0f - wy;
            #pragma unroll
            for (int k = 0; k < 4; k++) {
                bool hb = hs[k];
                float Alo0 = hb ? A0b : A0a, Ahi0 = hb ? A0c : A0b;
                float Alo1 = hb ? A1b : A1a, Ahi1 = hb ? A1c : A1b;
                float Blo0 = hb ? B0b : B0a, Bhi0 = hb ? B0c : B0b;
                float Blo1 = hb ? B1b : B1a, Bhi1 = hb ? B1c : B1b;
                float wx = wxv[k], omwx = 1.0f - wx;
                float Ar0 = Alo0 * omwx + Ahi0 * wx;
                float Ar1 = Alo1 * omwx + Ahi1 * wx;
                float Br0 = Blo0 * omwx + Bhi0 * wx;
                float Br1 = Blo1 * omwx + Bhi1 * wx;
                float Avv = Ar0 * omwy + Ar1 * wy;
                float Bvv = Br0 * omwy + Br1 * wy;
                ov[k] = Avv * hv[k] + Bvv;
            }
            float4 o; o.x = ov[0]; o.y = ov[1]; o.z = ov[2]; o.w = ov[3];
            o4[hidx] = o;
        }
    }
}

extern "C" void kernel_launch(void* const* d_in, const int* in_sizes, int n_in,
                              void* d_out, int out_size, void* d_ws, size_t ws_size,
                              hipStream_t stream) {
    const float* lr_x = (const float*)d_in[0];
    const float* lr_y = (const float*)d_in[1];
    const float* hr_x = (const float*)d_in[2];
    const float* l_a  = (const float*)d_in[3];
    float* out = (float*)d_out;

    float* ws       = (float*)d_ws;
    float* partials = ws;                 // 96 floats (pad to 256)
    float* HA       = ws + 256;
    float* HB       = HA + NC * PS;

    k_reduce<<<96, 256, 0, stream>>>(l_a, partials);
    k_ab    <<<1536, 256, 0, stream>>>(l_a, lr_x, lr_y, partials, HA, HB);
    k_tile  <<<3072, 256, 0, stream>>>(HA, HB, hr_x, out);
}